// Round 11
// baseline (327.989 us; speedup 1.0000x reference)
//
#include <hip/hip_runtime.h>
#include <hip/hip_bf16.h>

// Problem constants
#define M_DIM 256     // B*T
#define K_DIM 8192
#define N_DIM 8192
#define NGRP  64      // N/128 groups

// Tile config: 256-thread blocks (4 waves), BN=64 -> 1024 blocks = 4/CU
#define BN 64         // W rows per block
#define BK 32         // n per step
#define THREADS 256   // 4 waves; wave w owns m-range [64w, 64w+64), all 64 k
#define SPLITN 8
#define CHUNK  (N_DIM / SPLITN)   // 1024
#define NSTEPS (CHUNK / BK)       // 32
#define NG     (CHUNK >> 7)       // 8 groups per chunk

// LDS: A double-buffered (global_load_lds) + scales. B goes direct to regs.
#define ASIZE 16384               // bf16 [256][32]
#define SL_OFF (2 * ASIZE)        // 32768
#define LDS_TOTAL (SL_OFF + 64 * NG * 8)   // 36864 -> 4 blocks/CU

typedef __bf16 bf16x8 __attribute__((ext_vector_type(8)));
typedef __bf16 bf16x4 __attribute__((ext_vector_type(4)));
typedef float  f32x4  __attribute__((ext_vector_type(4)));

// XOR swizzle (involution): slot bits [6:4] ^= row bits [9:7] (A region)
#define SW(a) ((a) ^ ((((a) >> 7) & 7) << 4))

#define GLOAD_LDS16(g, l) __builtin_amdgcn_global_load_lds( \
    (const __attribute__((address_space(1))) void*)(g),     \
    (__attribute__((address_space(3))) void*)(l), 16, 0, 0)

// ---------------- Kernel 0: xs[m,n] = bf16(x[m,n] * mu1[n]) ----------------
__global__ __launch_bounds__(256) void prep_xs(const float* __restrict__ x,
                                               const float* __restrict__ mu1,
                                               __bf16* __restrict__ xs) {
    int t  = blockIdx.x * 256 + threadIdx.x;
    int n4 = t & 2047;
    int m  = t >> 11;
    int n  = n4 << 2;
    float4 xv = *(const float4*)(x + (size_t)m * N_DIM + n);
    float4 mv = *(const float4*)(mu1 + n);
    bf16x4 o;
    o[0] = (__bf16)(xv.x * mv.x);
    o[1] = (__bf16)(xv.y * mv.y);
    o[2] = (__bf16)(xv.z * mv.z);
    o[3] = (__bf16)(xv.w * mv.w);
    *(bf16x4*)(xs + (size_t)m * N_DIM + n) = o;
}

// ---------------- Kernel 1: 4-blocks/CU, B-direct, A-dbuf GEMM ----------------
__global__ __launch_bounds__(THREADS, 4)
void gemm_q(const __bf16* __restrict__ xs, const int* __restrict__ Wq,
            const float* __restrict__ scales, const float* __restrict__ zeros,
            __bf16* __restrict__ partial) {
    extern __shared__ __align__(1024) char lds[];

    const int b     = blockIdx.x;      // 1024 blocks
    const int split = b & 7;           // XCD-affine split
    const int kidx  = b >> 3;          // 0..127
    const int k0    = kidx * BN;
    const int nbase = split * CHUNK;
    const int gbase = split * NG;

    const int tid  = threadIdx.x;
    const int lane = tid & 63;
    const int w    = tid >> 6;               // 0..3 (m quarter: 64 rows)
    const int start = kidx & (NSTEPS - 1);   // n-rotation

    float* SL = (float*)(lds + SL_OFF);      // [NG][64] x {s, -z*s}

    // ---- stage scales/zeros (once): 512 pairs ----
    for (int e = tid; e < 64 * NG; e += THREADS) {
        int r = e & 63, g = e >> 6;
        size_t si = (size_t)(k0 + r) * NGRP + gbase + g;
        float s = scales[si];
        float z = zeros[si];
        float2 v; v.x = s; v.y = -z * s;
        *(float2*)&SL[(size_t)(g * 64 + r) * 2] = v;
    }
    asm volatile("s_waitcnt vmcnt(0) lgkmcnt(0)" ::: "memory");
    __builtin_amdgcn_s_barrier();

    // ---- A staging via global_load_lds: 4x 4KB chunks (16B/lane each) ----
    const char* asrc[4];
    int aoff[4];
#pragma unroll
    for (int cc = 0; cc < 4; ++cc) {
        int off = cc * 4096 + tid * 16;   // linear LDS dest in 16KB tile
        int L   = SW(off);                // inverse-swizzled source element
        aoff[cc] = off;
        asrc[cc] = (const char*)xs + ((size_t)(L >> 6) * N_DIM) * 2 + (L & 63);
    }

    // ---- B direct: for frag ci, lane reads row ci*16+(l&15), 8 codes ----
    const int* bptr[4];
#pragma unroll
    for (int ci = 0; ci < 4; ++ci)
        bptr[ci] = Wq + (size_t)(k0 + ci * 16 + (lane & 15)) * N_DIM + (lane >> 4) * 8;

    // A frag read offsets
    int ra[4];
#pragma unroll
    for (int mi = 0; mi < 4; ++mi)
        ra[mi] = SW((w * 64 + mi * 16 + (lane & 15)) * 64 + (lane >> 4) * 16);

#define ISSUE_A(t)                                                        \
    {                                                                     \
        int s_ = ((t) + start) & (NSTEPS - 1);                            \
        char* pb_ = lds + ((t) & 1) * ASIZE;                              \
        size_t so_ = (size_t)(nbase + s_ * BK) * 2;                       \
        _Pragma("unroll")                                                 \
        for (int cc = 0; cc < 4; ++cc)                                    \
            GLOAD_LDS16(asrc[cc] + so_, pb_ + aoff[cc]);                  \
    }
#define LOAD_B(t)                                                         \
    {                                                                     \
        int s_ = ((t) + start) & (NSTEPS - 1);                            \
        const int off_ = nbase + s_ * BK;                                 \
        _Pragma("unroll")                                                 \
        for (int ci = 0; ci < 4; ++ci) {                                  \
            qB[ci][0] = *(const int4*)(bptr[ci] + off_);                  \
            qB[ci][1] = *(const int4*)(bptr[ci] + off_ + 4);              \
        }                                                                 \
    }

    f32x4 acc[4][4];
#pragma unroll
    for (int i = 0; i < 4; ++i)
#pragma unroll
        for (int j = 0; j < 4; ++j)
            acc[i][j] = (f32x4){0.f, 0.f, 0.f, 0.f};

    int4 qB[4][2];
    float sc[4], zs[4];

    // prologue queue: [B(0) x8 | A(0) x4]
    LOAD_B(0);
    asm volatile("" ::: "memory");
    ISSUE_A(0);

    // STEP: vmcnt(4) [B(s) landed] | refresh scales | dequant -> bv |
    //       issue B(s+1) | vmcnt(W2) [A(s) landed] | barrier | issue A(s+1) |
    //       4 A-frags + 16 MFMA
#define STEP(it, W2, DO_NEXT)                                             \
    {                                                                     \
        asm volatile("s_waitcnt vmcnt(4)" ::: "memory");                  \
        int scur_ = ((it) + start) & (NSTEPS - 1);                        \
        if ((scur_ & 3) == 0 || (it) == 0) {                              \
            int g_ = scur_ >> 2;                                          \
            _Pragma("unroll")                                             \
            for (int ci = 0; ci < 4; ++ci) {                              \
                float2 v_ = *(float2*)&SL[(size_t)(g_ * 64 + ci * 16 + (lane & 15)) * 2]; \
                sc[ci] = v_.x; zs[ci] = v_.y;                             \
            }                                                             \
        }                                                                 \
        bf16x8 bv_[4];                                                    \
        _Pragma("unroll")                                                 \
        for (int ci = 0; ci < 4; ++ci) {                                  \
            bv_[ci][0] = (__bf16)((float)qB[ci][0].x * sc[ci] + zs[ci]);  \
            bv_[ci][1] = (__bf16)((float)qB[ci][0].y * sc[ci] + zs[ci]);  \
            bv_[ci][2] = (__bf16)((float)qB[ci][0].z * sc[ci] + zs[ci]);  \
            bv_[ci][3] = (__bf16)((float)qB[ci][0].w * sc[ci] + zs[ci]);  \
            bv_[ci][4] = (__bf16)((float)qB[ci][1].x * sc[ci] + zs[ci]);  \
            bv_[ci][5] = (__bf16)((float)qB[ci][1].y * sc[ci] + zs[ci]);  \
            bv_[ci][6] = (__bf16)((float)qB[ci][1].z * sc[ci] + zs[ci]);  \
            bv_[ci][7] = (__bf16)((float)qB[ci][1].w * sc[ci] + zs[ci]);  \
        }                                                                 \
        if (DO_NEXT) { LOAD_B((it) + 1); }                                \
        asm volatile("s_waitcnt vmcnt(" W2 ")" ::: "memory");             \
        __builtin_amdgcn_s_barrier();                                     \
        if (DO_NEXT) { ISSUE_A((it) + 1); }                               \
        const char* pA_ = lds + ((it) & 1) * ASIZE;                       \
        __builtin_amdgcn_s_setprio(1);                                    \
        _Pragma("unroll")                                                 \
        for (int mi = 0; mi < 4; ++mi) {                                  \
            bf16x8 av_ = *(const bf16x8*)(pA_ + ra[mi]);                  \
            acc[mi][0] = __builtin_amdgcn_mfma_f32_16x16x32_bf16(av_, bv_[0], acc[mi][0], 0, 0, 0); \
            acc[mi][1] = __builtin_amdgcn_mfma_f32_16x16x32_bf16(av_, bv_[1], acc[mi][1], 0, 0, 0); \
            acc[mi][2] = __builtin_amdgcn_mfma_f32_16x16x32_bf16(av_, bv_[2], acc[mi][2], 0, 0, 0); \
            acc[mi][3] = __builtin_amdgcn_mfma_f32_16x16x32_bf16(av_, bv_[3], acc[mi][3], 0, 0, 0); \
        }                                                                 \
        __builtin_amdgcn_s_setprio(0);                                    \
    }

    for (int it = 0; it < NSTEPS - 1; ++it) {
        STEP(it, "8", true);   // after B(s+1) issue: queue [A(s)x4, B(s+1)x8]
    }
    STEP(NSTEPS - 1, "0", false);
#undef STEP
#undef ISSUE_A
#undef LOAD_B

    // ---- epilogue: bf16 partials (C/D: col=lane&15, row=(lane>>4)*4+reg) ----
    __bf16* outp = partial + (size_t)split * ((size_t)M_DIM * K_DIM);
#pragma unroll
    for (int mi = 0; mi < 4; ++mi) {
#pragma unroll
        for (int ci = 0; ci < 4; ++ci) {
            int gk = k0 + ci * 16 + (lane & 15);
            int gm = w * 64 + mi * 16 + (lane >> 4) * 4;
#pragma unroll
            for (int rix = 0; rix < 4; ++rix)
                outp[(size_t)(gm + rix) * K_DIM + gk] = (__bf16)acc[mi][ci][rix];
        }
    }
}

// ---------------- Kernel 2: out = mu2[k] * sum_splits + bias[k] ----------------
__global__ __launch_bounds__(256) void reduce_out(const __bf16* __restrict__ partial,
                                                  const float* __restrict__ mu2,
                                                  const float* __restrict__ bias,
                                                  float* __restrict__ out) {
    int t  = blockIdx.x * 256 + threadIdx.x;
    int k4 = t & 2047;
    int m  = t >> 11;
    size_t base = (size_t)m * K_DIM + (size_t)k4 * 4;
    float4 s; s.x = 0.f; s.y = 0.f; s.z = 0.f; s.w = 0.f;
#pragma unroll
    for (int sp = 0; sp < SPLITN; ++sp) {
        bf16x4 p = *(const bf16x4*)(partial + (size_t)sp * ((size_t)M_DIM * K_DIM) + base);
        s.x += (float)p[0]; s.y += (float)p[1]; s.z += (float)p[2]; s.w += (float)p[3];
    }
    float4 m2 = *(const float4*)(mu2 + (size_t)k4 * 4);
    float4 bi = *(const float4*)(bias + (size_t)k4 * 4);
    float4 o;
    o.x = s.x * m2.x + bi.x;
    o.y = s.y * m2.y + bi.y;
    o.z = s.z * m2.z + bi.z;
    o.w = s.w * m2.w + bi.w;
    *(float4*)(out + base) = o;
}

extern "C" void kernel_launch(void* const* d_in, const int* in_sizes, int n_in,
                              void* d_out, int out_size, void* d_ws, size_t ws_size,
                              hipStream_t stream) {
    const float* x      = (const float*)d_in[0];
    const int*   Wq     = (const int*)d_in[1];
    const float* scales = (const float*)d_in[2];
    const float* zeros  = (const float*)d_in[3];
    const float* mu1    = (const float*)d_in[4];
    const float* mu2    = (const float*)d_in[5];
    const float* bias   = (const float*)d_in[6];
    float* out = (float*)d_out;

    __bf16* xs = (__bf16*)d_ws;                                        // 4 MB
    const size_t xs_bytes = (size_t)M_DIM * N_DIM * sizeof(__bf16);
    __bf16* partial = (__bf16*)((char*)d_ws + xs_bytes);               // 8 x 4 MB

    (void)hipFuncSetAttribute((const void*)gemm_q,
                              hipFuncAttributeMaxDynamicSharedMemorySize,
                              LDS_TOTAL);

    prep_xs<<<2048, 256, 0, stream>>>(x, mu1, xs);
    gemm_q<<<(K_DIM / BN) * SPLITN, THREADS, LDS_TOTAL, stream>>>(xs, Wq, scales, zeros, partial);
    reduce_out<<<2048, 256, 0, stream>>>(partial, mu2, bias, out);
}

// Round 12
// 166.976 us; speedup vs baseline: 1.9643x; 1.9643x over previous
//
#include <hip/hip_runtime.h>
#include <hip/hip_bf16.h>

// Problem constants
#define M_DIM 256     // B*T
#define K_DIM 8192
#define N_DIM 8192
#define NGRP  64      // N/128 groups

// Tile config (R10 structure: 8 waves = 4m x 2n, 2 blocks/CU)
#define BN 128        // W rows per block
#define BK 32         // n per step
#define THREADS 512
#define SPLITN 8
#define CHUNK  (N_DIM / SPLITN)   // 1024
#define NSTEPS (CHUNK / BK)       // 32
#define NPAIRS (NSTEPS / 2)       // 16
#define NG     (CHUNK >> 7)       // 8 groups per chunk

// LDS: A triple-buffered (global_load_lds) + B double-buffered bf16 + scales
#define ASIZE 16384               // bf16 [256][32]
#define BSIZE 8192                // bf16 [128][32]
#define B_OFF  (3 * ASIZE)        // 49152
#define SL_OFF (B_OFF + 2 * BSIZE)            // 65536
#define LDS_TOTAL (SL_OFF + NG * 128 * 8)     // 73728 (72KB) -> 2 blocks/CU

typedef __bf16 bf16x8 __attribute__((ext_vector_type(8)));
typedef __bf16 bf16x4 __attribute__((ext_vector_type(4)));
typedef float  f32x4  __attribute__((ext_vector_type(4)));
typedef int    i32x4  __attribute__((ext_vector_type(4)));

// XOR swizzle (involution): slot bits [6:4] ^= row bits [9:7]. Used for A and B.
#define SW(a) ((a) ^ ((((a) >> 7) & 7) << 4))

#define GLOAD_LDS16(g, l) __builtin_amdgcn_global_load_lds( \
    (const __attribute__((address_space(1))) void*)(g),     \
    (__attribute__((address_space(3))) void*)(l), 16, 0, 0)

#define NT4(p) __builtin_nontemporal_load((const i32x4*)(p))

// pair-granular n-rotation: step t -> actual step; pairs stay contiguous
#define SMAP(t) (((((((t) >> 1) + startp) & (NPAIRS - 1))) << 1) | ((t) & 1))

// ---------------- Kernel 0: xs[m,n] = bf16(x[m,n] * mu1[n]) ----------------
__global__ __launch_bounds__(256) void prep_xs(const float* __restrict__ x,
                                               const float* __restrict__ mu1,
                                               __bf16* __restrict__ xs) {
    int t  = blockIdx.x * 256 + threadIdx.x;
    int n4 = t & 2047;
    int m  = t >> 11;
    int n  = n4 << 2;
    float4 xv = *(const float4*)(x + (size_t)m * N_DIM + n);
    float4 mv = *(const float4*)(mu1 + n);
    bf16x4 o;
    o[0] = (__bf16)(xv.x * mv.x);
    o[1] = (__bf16)(xv.y * mv.y);
    o[2] = (__bf16)(xv.z * mv.z);
    o[3] = (__bf16)(xv.w * mv.w);
    *(bf16x4*)(xs + (size_t)m * N_DIM + n) = o;
}

// ---------------- Kernel 1: R10 + B pair-fetch (256B/row-visit, nt) ----------------
__global__ __launch_bounds__(THREADS, 4)
void gemm_q(const __bf16* __restrict__ xs, const int* __restrict__ Wq,
            const float* __restrict__ scales, const float* __restrict__ zeros,
            __bf16* __restrict__ partial) {
    extern __shared__ __align__(1024) char lds[];

    const int b     = blockIdx.x;      // 512 blocks
    const int split = b & 7;           // XCD-affine split
    const int kidx  = b >> 3;          // 0..63
    const int k0    = kidx * BN;
    const int nbase = split * CHUNK;
    const int gbase = split * NG;

    const int tid  = threadIdx.x;
    const int lane = tid & 63;
    const int w    = tid >> 6;   // 0..7
    const int wmq  = w >> 1;     // m quarter (64 rows)
    const int wnh  = w & 1;      // k half (64 cols)
    const int startp = kidx & (NPAIRS - 1);  // pair-granular n-rotation

    float* SL = (float*)(lds + SL_OFF);      // [NG][128] x {s, -z*s}

    // ---- stage scales/zeros (once) ----
    {
        int r = tid >> 2, gq = tid & 3;
#pragma unroll
        for (int gg = 0; gg < (NG >> 2); ++gg) {
            int g = (gg << 2) | gq;
            size_t si = (size_t)(k0 + r) * NGRP + gbase + g;
            float s = scales[si];
            float z = zeros[si];
            float2 v; v.x = s; v.y = -z * s;
            *(float2*)&SL[(size_t)((g << 7) + r) * 2] = v;
        }
    }
    // full drain so the vmcnt ledger starts at 0
    asm volatile("s_waitcnt vmcnt(0) lgkmcnt(0)" ::: "memory");
    __builtin_amdgcn_s_barrier();

    // ---- A staging via global_load_lds: 2x 1KB chunks per wave ----
    const char* asrc[2];
    int aoff[2];
#pragma unroll
    for (int cc = 0; cc < 2; ++cc) {
        int c   = w * 2 + cc;            // 0..15
        int off = c * 1024 + lane * 16;  // linear LDS dest
        int L   = SW(off);               // inverse-swizzled source element
        aoff[cc] = off;
        asrc[cc] = (const char*)xs + ((size_t)(L >> 6) * N_DIM) * 2 + (L & 63);
    }

    // ---- B staging: lane owns row 16w+(l>>2), 8 codes at col (l&3)*8 ----
    const int brow = w * 16 + (lane >> 2);        // 0..127
    const int bq   = lane & 3;
    const int* bptr0 = Wq + (size_t)(k0 + brow) * N_DIM + bq * 8;
    char* bdst0 = lds + B_OFF + SW(brow * 64 + bq * 16);  // swizzled B write

    // B frag read offsets (4 ci tiles), A frag read offsets (4 mi tiles)
    int rb[4], ra[4];
#pragma unroll
    for (int i = 0; i < 4; ++i) {
        rb[i] = SW((wnh * 64 + i * 16 + (lane & 15)) * 64 + (lane >> 4) * 16);
        ra[i] = SW((wmq * 64 + i * 16 + (lane & 15)) * 64 + (lane >> 4) * 16);
    }

    // rotating A buffers: pA0 = read(s), pA1 = s+1, pA2 = issue target (s+2)
    char* pA0 = lds;
    char* pA1 = lds + ASIZE;
    char* pA2 = lds + 2 * ASIZE;

#define ISSUE_A(t, pbuf)                                                  \
    {                                                                     \
        int s_ = SMAP(t);                                                 \
        size_t so_ = (size_t)(nbase + s_ * BK) * 2;                       \
        GLOAD_LDS16(asrc[0] + so_, (pbuf) + aoff[0]);                     \
        GLOAD_LDS16(asrc[1] + so_, (pbuf) + aoff[1]);                     \
    }
// load BOTH steps of pair starting at even step t: 256B contiguous per row
#define LOAD_BPAIR(t, a0, a1, a2, a3)                                     \
    {                                                                     \
        int s_ = SMAP(t);                                                 \
        const int* p_ = bptr0 + (nbase + s_ * BK);                        \
        a0 = NT4(p_);                                                     \
        a1 = NT4(p_ + 4);                                                 \
        a2 = NT4(p_ + 32);                                                \
        a3 = NT4(p_ + 36);                                                \
    }

    f32x4 acc[4][4];
#pragma unroll
    for (int i = 0; i < 4; ++i)
#pragma unroll
        for (int j = 0; j < 4; ++j)
            acc[i][j] = (f32x4){0.f, 0.f, 0.f, 0.f};

    i32x4 pq0, pq1, pq2, pq3, rq0, rq1, rq2, rq3;

    // prologue queue: [Bpair0(4) | A(0)2 | A(1)2 | Bpair1(4)] = 12 outstanding
    LOAD_BPAIR(0, pq0, pq1, pq2, pq3);
    asm volatile("" ::: "memory");
    ISSUE_A(0, pA0);
    asm volatile("" ::: "memory");
    ISSUE_A(1, pA1);
    asm volatile("" ::: "memory");
    LOAD_BPAIR(2, rq0, rq1, rq2, rq3);

    // STEP: vmcnt(W) | dequant B(it) from regs -> swizzled LDS | BLOAD (odd
    // steps: next-next pair into just-consumed set) | lgkm+barrier | B frags |
    // issue A(it+2) | MFMA on pA0 | rotate A bufs.
    // Ledger (insts): steady entry even=[Bp(p)4,A(s)2,A(s+1)2,Bp(p+1)4]=12 ->
    // vmcnt(6); odd=[A(s)2,Bp(p+1)4,A(s+1)2]=8 -> vmcnt(6). Tail 6/6/2/0.
#define STEP(it, q0c, q1c, WSTR, BLOAD, DO_A)                             \
    {                                                                     \
        asm volatile("s_waitcnt vmcnt(" WSTR ")" ::: "memory");           \
        int scur_ = SMAP(it);                                             \
        float2 sz_ = *(float2*)&SL[(size_t)(((scur_ >> 2) << 7) + brow) * 2]; \
        bf16x8 wv_;                                                       \
        wv_[0] = (__bf16)((float)q0c[0] * sz_.x + sz_.y);                 \
        wv_[1] = (__bf16)((float)q0c[1] * sz_.x + sz_.y);                 \
        wv_[2] = (__bf16)((float)q0c[2] * sz_.x + sz_.y);                 \
        wv_[3] = (__bf16)((float)q0c[3] * sz_.x + sz_.y);                 \
        wv_[4] = (__bf16)((float)q1c[0] * sz_.x + sz_.y);                 \
        wv_[5] = (__bf16)((float)q1c[1] * sz_.x + sz_.y);                 \
        wv_[6] = (__bf16)((float)q1c[2] * sz_.x + sz_.y);                 \
        wv_[7] = (__bf16)((float)q1c[3] * sz_.x + sz_.y);                 \
        *(bf16x8*)(bdst0 + ((it) & 1) * BSIZE) = wv_;                     \
        BLOAD;                                                            \
        asm volatile("s_waitcnt lgkmcnt(0)" ::: "memory");                \
        __builtin_amdgcn_s_barrier();                                     \
        const char* bufB_ = lds + B_OFF + ((it) & 1) * BSIZE;             \
        bf16x8 bv0_ = *(const bf16x8*)(bufB_ + rb[0]);                    \
        bf16x8 bv1_ = *(const bf16x8*)(bufB_ + rb[1]);                    \
        bf16x8 bv2_ = *(const bf16x8*)(bufB_ + rb[2]);                    \
        bf16x8 bv3_ = *(const bf16x8*)(bufB_ + rb[3]);                    \
        if (DO_A) { ISSUE_A((it) + 2, pA2); }                             \
        __builtin_amdgcn_s_setprio(1);                                    \
        _Pragma("unroll")                                                 \
        for (int mi = 0; mi < 4; ++mi) {                                  \
            bf16x8 av_ = *(const bf16x8*)(pA0 + ra[mi]);                  \
            acc[mi][0] = __builtin_amdgcn_mfma_f32_16x16x32_bf16(av_, bv0_, acc[mi][0], 0, 0, 0); \
            acc[mi][1] = __builtin_amdgcn_mfma_f32_16x16x32_bf16(av_, bv1_, acc[mi][1], 0, 0, 0); \
            acc[mi][2] = __builtin_amdgcn_mfma_f32_16x16x32_bf16(av_, bv2_, acc[mi][2], 0, 0, 0); \
            acc[mi][3] = __builtin_amdgcn_mfma_f32_16x16x32_bf16(av_, bv3_, acc[mi][3], 0, 0, 0); \
        }                                                                 \
        __builtin_amdgcn_s_setprio(0);                                    \
        { char* t_ = pA0; pA0 = pA1; pA1 = pA2; pA2 = t_; }               \
    }

#define NOB {}
    for (int it = 0; it < NSTEPS - 4; it += 4) {
        STEP(it,     pq0, pq1, "6", NOB, true);
        STEP(it + 1, pq2, pq3, "6", LOAD_BPAIR((it) + 4, pq0, pq1, pq2, pq3), true);
        STEP(it + 2, rq0, rq1, "6", NOB, true);
        STEP(it + 3, rq2, rq3, "6", LOAD_BPAIR((it) + 6, rq0, rq1, rq2, rq3), true);
    }
    STEP(NSTEPS - 4, pq0, pq1, "6", NOB, true);    // issues A(30)
    STEP(NSTEPS - 3, pq2, pq3, "6", NOB, true);    // issues A(31)
    STEP(NSTEPS - 2, rq0, rq1, "2", NOB, false);
    STEP(NSTEPS - 1, rq2, rq3, "0", NOB, false);
#undef NOB
#undef STEP
#undef ISSUE_A
#undef LOAD_BPAIR

    // ---- epilogue: bf16 partials (C/D: col=lane&15, row=(lane>>4)*4+reg) ----
    __bf16* outp = partial + (size_t)split * ((size_t)M_DIM * K_DIM);
#pragma unroll
    for (int mi = 0; mi < 4; ++mi) {
#pragma unroll
        for (int ci = 0; ci < 4; ++ci) {
            int gk = k0 + wnh * 64 + ci * 16 + (lane & 15);
            int gm = wmq * 64 + mi * 16 + (lane >> 4) * 4;
#pragma unroll
            for (int rix = 0; rix < 4; ++rix)
                outp[(size_t)(gm + rix) * K_DIM + gk] = (__bf16)acc[mi][ci][rix];
        }
    }
}

// ---------------- Kernel 2: out = mu2[k] * sum_splits + bias[k] ----------------
__global__ __launch_bounds__(256) void reduce_out(const __bf16* __restrict__ partial,
                                                  const float* __restrict__ mu2,
                                                  const float* __restrict__ bias,
                                                  float* __restrict__ out) {
    int t  = blockIdx.x * 256 + threadIdx.x;
    int k4 = t & 2047;
    int m  = t >> 11;
    size_t base = (size_t)m * K_DIM + (size_t)k4 * 4;
    float4 s; s.x = 0.f; s.y = 0.f; s.z = 0.f; s.w = 0.f;
#pragma unroll
    for (int sp = 0; sp < SPLITN; ++sp) {
        bf16x4 p = *(const bf16x4*)(partial + (size_t)sp * ((size_t)M_DIM * K_DIM) + base);
        s.x += (float)p[0]; s.y += (float)p[1]; s.z += (float)p[2]; s.w += (float)p[3];
    }
    float4 m2 = *(const float4*)(mu2 + (size_t)k4 * 4);
    float4 bi = *(const float4*)(bias + (size_t)k4 * 4);
    float4 o;
    o.x = s.x * m2.x + bi.x;
    o.y = s.y * m2.y + bi.y;
    o.z = s.z * m2.z + bi.z;
    o.w = s.w * m2.w + bi.w;
    *(float4*)(out + base) = o;
}

extern "C" void kernel_launch(void* const* d_in, const int* in_sizes, int n_in,
                              void* d_out, int out_size, void* d_ws, size_t ws_size,
                              hipStream_t stream) {
    const float* x      = (const float*)d_in[0];
    const int*   Wq     = (const int*)d_in[1];
    const float* scales = (const float*)d_in[2];
    const float* zeros  = (const float*)d_in[3];
    const float* mu1    = (const float*)d_in[4];
    const float* mu2    = (const float*)d_in[5];
    const float* bias   = (const float*)d_in[6];
    float* out = (float*)d_out;

    __bf16* xs = (__bf16*)d_ws;                                        // 4 MB
    const size_t xs_bytes = (size_t)M_DIM * N_DIM * sizeof(__bf16);
    __bf16* partial = (__bf16*)((char*)d_ws + xs_bytes);               // 8 x 4 MB

    (void)hipFuncSetAttribute((const void*)gemm_q,
                              hipFuncAttributeMaxDynamicSharedMemorySize,
                              LDS_TOTAL);

    prep_xs<<<2048, 256, 0, stream>>>(x, mu1, xs);
    gemm_q<<<64 * SPLITN, THREADS, LDS_TOTAL, stream>>>(xs, Wq, scales, zeros, partial);
    reduce_out<<<2048, 256, 0, stream>>>(partial, mu2, bias, out);
}

// Round 13
// 112.303 us; speedup vs baseline: 2.9206x; 1.4868x over previous
//
#include <hip/hip_runtime.h>
#include <hip/hip_bf16.h>

// Problem constants
#define M_DIM 256     // B*T
#define K_DIM 8192
#define N_DIM 8192
#define NGRP  64      // N/128 groups

// Tile config: 4-wave blocks -> 4 independent barrier domains per CU
#define BN 64         // W rows per block
#define BK 32         // n per step
#define THREADS 256   // 4 waves; wave w owns m-rows [64w,64w+64) x all 64 k
#define SPLITN 8
#define CHUNK  (N_DIM / SPLITN)   // 1024
#define NSTEPS (CHUNK / BK)       // 32
#define NG     (CHUNK >> 7)       // 8 groups per chunk

// LDS: A single-buffered [256][32] bf16 + B double-buffered [64][32] bf16 + SL
#define ASIZE 16384
#define BSIZE 4096
#define B_OFF  ASIZE                      // 16384
#define SL_OFF (ASIZE + 2 * BSIZE)        // 24576
#define LDS_TOTAL (SL_OFF + NG * 64 * 8)  // 28672 -> 4 blocks/CU (reg-capped too)

typedef __bf16 bf16x8 __attribute__((ext_vector_type(8)));
typedef __bf16 bf16x4 __attribute__((ext_vector_type(4)));
typedef float  f32x4  __attribute__((ext_vector_type(4)));

// XOR swizzle (involution): slot bits [6:4] ^= row bits [9:7]. A and B regions.
#define SW(a) ((a) ^ ((((a) >> 7) & 7) << 4))

#define GLOAD_LDS16(g, l) __builtin_amdgcn_global_load_lds( \
    (const __attribute__((address_space(1))) void*)(g),     \
    (__attribute__((address_space(3))) void*)(l), 16, 0, 0)

// ---------------- Kernel 0: xs[m,n] = bf16(x[m,n] * mu1[n]) ----------------
__global__ __launch_bounds__(256) void prep_xs(const float* __restrict__ x,
                                               const float* __restrict__ mu1,
                                               __bf16* __restrict__ xs) {
    int t  = blockIdx.x * 256 + threadIdx.x;
    int n4 = t & 2047;
    int m  = t >> 11;
    int n  = n4 << 2;
    float4 xv = *(const float4*)(x + (size_t)m * N_DIM + n);
    float4 mv = *(const float4*)(mu1 + n);
    bf16x4 o;
    o[0] = (__bf16)(xv.x * mv.x);
    o[1] = (__bf16)(xv.y * mv.y);
    o[2] = (__bf16)(xv.z * mv.z);
    o[3] = (__bf16)(xv.w * mv.w);
    *(bf16x4*)(xs + (size_t)m * N_DIM + n) = o;
}

// ---------------- Kernel 1: 4-domain/CU split-K GEMM ----------------
__global__ __launch_bounds__(THREADS, 4)
void gemm_q(const __bf16* __restrict__ xs, const int* __restrict__ Wq,
            const float* __restrict__ scales, const float* __restrict__ zeros,
            __bf16* __restrict__ partial) {
    extern __shared__ __align__(1024) char lds[];

    const int b     = blockIdx.x;      // 1024 blocks
    const int split = b & 7;           // XCD-affine split
    const int kidx  = b >> 3;          // 0..127
    const int k0    = kidx * BN;
    const int nbase = split * CHUNK;
    const int gbase = split * NG;

    const int tid  = threadIdx.x;
    const int lane = tid & 63;
    const int w    = tid >> 6;               // 0..3 (m quarter)
    const int start = kidx & (NSTEPS - 1);   // n-rotation

    float* SL = (float*)(lds + SL_OFF);      // [NG][64] x {s, -z*s}

    // ---- stage scales/zeros (once): 512 pairs, 2 per thread ----
    {
        int e0 = tid;          // covers [0,256)
        int e1 = tid + 256;    // covers [256,512)
#pragma unroll
        for (int pass = 0; pass < 2; ++pass) {
            int e = pass ? e1 : e0;
            int r = e & 63, g = e >> 6;
            size_t si = (size_t)(k0 + r) * NGRP + gbase + g;
            float s = scales[si];
            float z = zeros[si];
            float2 v; v.x = s; v.y = -z * s;
            *(float2*)&SL[(size_t)((g << 6) + r) * 2] = v;
        }
    }
    asm volatile("s_waitcnt vmcnt(0) lgkmcnt(0)" ::: "memory");
    __builtin_amdgcn_s_barrier();

    // ---- A staging via global_load_lds: 4x 4KB chunks (16B/thread each) ----
    const char* asrc[4];
    int aoff[4];
#pragma unroll
    for (int cc = 0; cc < 4; ++cc) {
        int off = cc * 4096 + tid * 16;   // linear LDS dest in single 16KB tile
        int L   = SW(off);                // inverse-swizzled source element
        aoff[cc] = off;
        asrc[cc] = (const char*)xs + ((size_t)(L >> 6) * N_DIM) * 2 + (L & 63);
    }

    // ---- B staging: lane owns row tid>>2 (0..63), 8 codes at col (tid&3)*8 ----
    const int brow = tid >> 2;
    const int bq   = tid & 3;
    const int* bptr0 = Wq + (size_t)(k0 + brow) * N_DIM + bq * 8;
    char* bdst0 = lds + B_OFF + SW(brow * 64 + bq * 16);  // swizzled B write

    // frag read offsets: B (4 ci tiles), A (4 mi tiles)
    int rb[4], ra[4];
#pragma unroll
    for (int i = 0; i < 4; ++i) {
        rb[i] = SW((i * 16 + (lane & 15)) * 64 + (lane >> 4) * 16);
        ra[i] = SW((w * 64 + i * 16 + (lane & 15)) * 64 + (lane >> 4) * 16);
    }

#define ISSUE_A(t)                                                        \
    {                                                                     \
        int s_ = ((t) + start) & (NSTEPS - 1);                            \
        size_t so_ = (size_t)(nbase + s_ * BK) * 2;                       \
        _Pragma("unroll")                                                 \
        for (int cc = 0; cc < 4; ++cc)                                    \
            GLOAD_LDS16(asrc[cc] + so_, lds + aoff[cc]);                  \
    }
#define LOAD_B(t, q0, q1)                                                 \
    {                                                                     \
        int s_ = ((t) + start) & (NSTEPS - 1);                            \
        const int* p_ = bptr0 + (nbase + s_ * BK);                        \
        q0 = *(const int4*)p_;                                            \
        q1 = *(const int4*)(p_ + 4);                                      \
    }

    f32x4 acc[4][4];
#pragma unroll
    for (int i = 0; i < 4; ++i)
#pragma unroll
        for (int j = 0; j < 4; ++j)
            acc[i][j] = (f32x4){0.f, 0.f, 0.f, 0.f};

    int4 qa0, qa1, qb0, qb1;

    // prologue FIFO: [B0(2), B1(2), A0(4)] = 8; drain B0 -> vmcnt(6).
    LOAD_B(0, qa0, qa1);
    asm volatile("" ::: "memory");
    LOAD_B(1, qb0, qb1);
    asm volatile("" ::: "memory");
    ISSUE_A(0);
    asm volatile("s_waitcnt vmcnt(6)" ::: "memory");

    // STEP: dequant B(it) regs->LDS[it&1] | issue B(it+2) | vmcnt(W)+lgkm(0)
    // [A(it) landed, own writes drained] | barrier | frags+MFMA | barrier |
    // issue A(it+1) into the single A buffer (safe: all reads done).
    // Steady ledger: entry [B(it+1)2, A(it)4]; +B(it+2)2; drain A(it) -> vmcnt(2).
#define STEP(it, q0c, q1c, WSTR, DO_B, DO_A)                              \
    {                                                                     \
        int scur_ = ((it) + start) & (NSTEPS - 1);                        \
        float2 sz_ = *(float2*)&SL[(size_t)(((scur_ >> 2) << 6) + brow) * 2]; \
        bf16x8 wv_;                                                       \
        wv_[0] = (__bf16)((float)q0c.x * sz_.x + sz_.y);                  \
        wv_[1] = (__bf16)((float)q0c.y * sz_.x + sz_.y);                  \
        wv_[2] = (__bf16)((float)q0c.z * sz_.x + sz_.y);                  \
        wv_[3] = (__bf16)((float)q0c.w * sz_.x + sz_.y);                  \
        wv_[4] = (__bf16)((float)q1c.x * sz_.x + sz_.y);                  \
        wv_[5] = (__bf16)((float)q1c.y * sz_.x + sz_.y);                  \
        wv_[6] = (__bf16)((float)q1c.z * sz_.x + sz_.y);                  \
        wv_[7] = (__bf16)((float)q1c.w * sz_.x + sz_.y);                  \
        *(bf16x8*)(bdst0 + ((it) & 1) * BSIZE) = wv_;                     \
        if (DO_B) { LOAD_B((it) + 2, q0c, q1c); }                         \
        asm volatile("s_waitcnt vmcnt(" WSTR ") lgkmcnt(0)" ::: "memory"); \
        __builtin_amdgcn_s_barrier();                                     \
        const char* bufB_ = lds + B_OFF + ((it) & 1) * BSIZE;             \
        bf16x8 bv0_ = *(const bf16x8*)(bufB_ + rb[0]);                    \
        bf16x8 bv1_ = *(const bf16x8*)(bufB_ + rb[1]);                    \
        bf16x8 bv2_ = *(const bf16x8*)(bufB_ + rb[2]);                    \
        bf16x8 bv3_ = *(const bf16x8*)(bufB_ + rb[3]);                    \
        __builtin_amdgcn_s_setprio(1);                                    \
        _Pragma("unroll")                                                 \
        for (int mi = 0; mi < 4; ++mi) {                                  \
            bf16x8 av_ = *(const bf16x8*)(lds + ra[mi]);                  \
            acc[mi][0] = __builtin_amdgcn_mfma_f32_16x16x32_bf16(av_, bv0_, acc[mi][0], 0, 0, 0); \
            acc[mi][1] = __builtin_amdgcn_mfma_f32_16x16x32_bf16(av_, bv1_, acc[mi][1], 0, 0, 0); \
            acc[mi][2] = __builtin_amdgcn_mfma_f32_16x16x32_bf16(av_, bv2_, acc[mi][2], 0, 0, 0); \
            acc[mi][3] = __builtin_amdgcn_mfma_f32_16x16x32_bf16(av_, bv3_, acc[mi][3], 0, 0, 0); \
        }                                                                 \
        __builtin_amdgcn_s_setprio(0);                                    \
        __builtin_amdgcn_s_barrier();                                     \
        if (DO_A) { ISSUE_A((it) + 1); }                                  \
    }

    for (int it = 0; it < NSTEPS - 2; it += 2) {
        STEP(it,     qa0, qa1, "2", true, true);
        STEP(it + 1, qb0, qb1, "2", true, true);
    }
    STEP(NSTEPS - 2, qa0, qa1, "0", false, true);
    STEP(NSTEPS - 1, qb0, qb1, "0", false, false);
#undef STEP
#undef ISSUE_A
#undef LOAD_B

    // ---- epilogue: bf16 partials (C/D: col=lane&15, row=(lane>>4)*4+reg) ----
    __bf16* outp = partial + (size_t)split * ((size_t)M_DIM * K_DIM);
#pragma unroll
    for (int mi = 0; mi < 4; ++mi) {
#pragma unroll
        for (int ci = 0; ci < 4; ++ci) {
            int gk = k0 + ci * 16 + (lane & 15);
            int gm = w * 64 + mi * 16 + (lane >> 4) * 4;
#pragma unroll
            for (int rix = 0; rix < 4; ++rix)
                outp[(size_t)(gm + rix) * K_DIM + gk] = (__bf16)acc[mi][ci][rix];
        }
    }
}

// ---------------- Kernel 2: out = mu2[k] * sum_splits + bias[k] ----------------
__global__ __launch_bounds__(256) void reduce_out(const __bf16* __restrict__ partial,
                                                  const float* __restrict__ mu2,
                                                  const float* __restrict__ bias,
                                                  float* __restrict__ out) {
    int t  = blockIdx.x * 256 + threadIdx.x;
    int k4 = t & 2047;
    int m  = t >> 11;
    size_t base = (size_t)m * K_DIM + (size_t)k4 * 4;
    float4 s; s.x = 0.f; s.y = 0.f; s.z = 0.f; s.w = 0.f;
#pragma unroll
    for (int sp = 0; sp < SPLITN; ++sp) {
        bf16x4 p = *(const bf16x4*)(partial + (size_t)sp * ((size_t)M_DIM * K_DIM) + base);
        s.x += (float)p[0]; s.y += (float)p[1]; s.z += (float)p[2]; s.w += (float)p[3];
    }
    float4 m2 = *(const float4*)(mu2 + (size_t)k4 * 4);
    float4 bi = *(const float4*)(bias + (size_t)k4 * 4);
    float4 o;
    o.x = s.x * m2.x + bi.x;
    o.y = s.y * m2.y + bi.y;
    o.z = s.z * m2.z + bi.z;
    o.w = s.w * m2.w + bi.w;
    *(float4*)(out + base) = o;
}

extern "C" void kernel_launch(void* const* d_in, const int* in_sizes, int n_in,
                              void* d_out, int out_size, void* d_ws, size_t ws_size,
                              hipStream_t stream) {
    const float* x      = (const float*)d_in[0];
    const int*   Wq     = (const int*)d_in[1];
    const float* scales = (const float*)d_in[2];
    const float* zeros  = (const float*)d_in[3];
    const float* mu1    = (const float*)d_in[4];
    const float* mu2    = (const float*)d_in[5];
    const float* bias   = (const float*)d_in[6];
    float* out = (float*)d_out;

    __bf16* xs = (__bf16*)d_ws;                                        // 4 MB
    const size_t xs_bytes = (size_t)M_DIM * N_DIM * sizeof(__bf16);
    __bf16* partial = (__bf16*)((char*)d_ws + xs_bytes);               // 8 x 4 MB

    (void)hipFuncSetAttribute((const void*)gemm_q,
                              hipFuncAttributeMaxDynamicSharedMemorySize,
                              LDS_TOTAL);

    prep_xs<<<2048, 256, 0, stream>>>(x, mu1, xs);
    gemm_q<<<(K_DIM / BN) * SPLITN, THREADS, LDS_TOTAL, stream>>>(xs, Wq, scales, zeros, partial);
    reduce_out<<<2048, 256, 0, stream>>>(partial, mu2, bias, out);
}